// Round 1
// baseline (290.585 us; speedup 1.0000x reference)
//
#include <hip/hip_runtime.h>

// Spline2D: out[b,R,C] = sum_{i,j} wx[i]*wy[j]*coeffs[(R-px-96)+2+i, (C-py-96)+2+j]
// when (R-px-96) in [0,64] and (C-py-96) in [0,64], else 0.
// px=floor(x[b]), py=floor(y[b]); wx=bspline3(frac(x)), wy=bspline3(frac(y)).

#define TH 64
#define TW 64
#define CW 72          // coeffs leading dim (TH + 2*PAD)
#define NBLK_PER_IMG 64  // 65536 floats / (256 thr * 4 floats)

__global__ __launch_bounds__(256) void spline2d_kernel(
    const float* __restrict__ coeffs,
    const float* __restrict__ x,
    const float* __restrict__ y,
    float* __restrict__ out)
{
    const int gid = blockIdx.x * 256 + threadIdx.x;  // one float4 per thread
    const int b   = gid >> 14;       // 16384 float4 per image
    const int rem = gid & 16383;
    const int R   = rem >> 6;        // output row 0..255
    const int C0  = (rem & 63) << 2; // first of 4 output cols

    const float xv = x[b];
    const float yv = y[b];
    const float fx = floorf(xv), fy = floorf(yv);
    const int   px = (int)fx,    py = (int)fy;
    const float sx = xv - fx,    sy = yv - fy;

    const int r = R - px - 96;

    float4 o = make_float4(0.f, 0.f, 0.f, 0.f);

    if (r >= 0 && r <= TH) {
        // cubic B-spline basis weights
        float wx0, wx1, wx2, wx3, wy0, wy1, wy2, wy3;
        {
            const float p = sx, p2 = p * p, p3 = p2 * p, q = 1.0f - p;
            wx0 = p3 * (1.0f / 6.0f);
            wx1 = -0.5f * p3 + 0.5f * p2 + 0.5f * p + (1.0f / 6.0f);
            wx2 = 0.5f * p3 - p2 + (2.0f / 3.0f);
            wx3 = q * q * q * (1.0f / 6.0f);
        }
        {
            const float p = sy, p2 = p * p, p3 = p2 * p, q = 1.0f - p;
            wy0 = p3 * (1.0f / 6.0f);
            wy1 = -0.5f * p3 + 0.5f * p2 + 0.5f * p + (1.0f / 6.0f);
            wy2 = 0.5f * p3 - p2 + (2.0f / 3.0f);
            wy3 = q * q * q * (1.0f / 6.0f);
        }

        const int cbase = C0 - py - 96;
        float vals[4];
#pragma unroll
        for (int e = 0; e < 4; ++e) {
            const int c = cbase + e;
            float v = 0.0f;
            if (c >= 0 && c <= TW) {
                const float* p0 = coeffs + (r + 2) * CW + (c + 2);
#pragma unroll
                for (int i = 0; i < 4; ++i) {
                    const float* row = p0 + i * CW;
                    const float s = row[0] * wy0 + row[1] * wy1 +
                                    row[2] * wy2 + row[3] * wy3;
                    v = fmaf((i == 0 ? wx0 : i == 1 ? wx1 : i == 2 ? wx2 : wx3), s, v);
                }
            }
            vals[e] = v;
        }
        o = make_float4(vals[0], vals[1], vals[2], vals[3]);
    }

    reinterpret_cast<float4*>(out)[gid] = o;
}

extern "C" void kernel_launch(void* const* d_in, const int* in_sizes, int n_in,
                              void* d_out, int out_size, void* d_ws, size_t ws_size,
                              hipStream_t stream) {
    const float* coeffs = (const float*)d_in[0];  // (72,72)
    const float* x      = (const float*)d_in[1];  // (1024,)
    const float* y      = (const float*)d_in[2];  // (1024,)
    float* out = (float*)d_out;                   // (1024,1,256,256)

    // total float4 = 1024 * 256 * 256 / 4 = 16,777,216 -> 65536 blocks of 256
    const int nblocks = (out_size / 4 + 255) / 256;
    spline2d_kernel<<<nblocks, 256, 0, stream>>>(coeffs, x, y, out);
}

// Round 2
// 268.297 us; speedup vs baseline: 1.0831x; 1.0831x over previous
//
#include <hip/hip_runtime.h>

// Spline2D restructured as: (1) hipMemsetAsync zero-fill of the 256 MiB output
// (ROCm fill kernel streams at ~6.5 TB/s), (2) a patch kernel that computes and
// writes only the 65x65 nonzero window per batch image (~17 MB total).
//
// out[b,R,C] = sum_{i,j} wx[i]*wy[j]*coeffs[(R-px-96)+2+i, (C-py-96)+2+j]
// for (R-px-96),(C-py-96) in [0,64]; zero elsewhere.

#define CW 72   // coeffs leading dim (64 + 2*4)
#define PATCH 65
#define PATCH_ELEMS (PATCH * PATCH)   // 4225

__global__ __launch_bounds__(256) void spline2d_patch(
    const float* __restrict__ coeffs,
    const float* __restrict__ x,
    const float* __restrict__ y,
    float* __restrict__ out)
{
    const int b = blockIdx.x;

    const float xv = x[b];
    const float yv = y[b];
    const float fx = floorf(xv), fy = floorf(yv);
    const int   px = (int)fx,    py = (int)fy;
    const float sx = xv - fx,    sy = yv - fy;

    float wx[4], wy[4];
    {
        const float p = sx, p2 = p * p, p3 = p2 * p, q = 1.0f - p;
        wx[0] = p3 * (1.0f / 6.0f);
        wx[1] = -0.5f * p3 + 0.5f * p2 + 0.5f * p + (1.0f / 6.0f);
        wx[2] = 0.5f * p3 - p2 + (2.0f / 3.0f);
        wx[3] = q * q * q * (1.0f / 6.0f);
    }
    {
        const float p = sy, p2 = p * p, p3 = p2 * p, q = 1.0f - p;
        wy[0] = p3 * (1.0f / 6.0f);
        wy[1] = -0.5f * p3 + 0.5f * p2 + 0.5f * p + (1.0f / 6.0f);
        wy[2] = 0.5f * p3 - p2 + (2.0f / 3.0f);
        wy[3] = q * q * q * (1.0f / 6.0f);
    }

    const int R0 = px + 96;   // top row of patch in output
    const int C0 = py + 96;   // left col of patch in output
    float* __restrict__ ob = out + (size_t)b * 65536;

    for (int e = threadIdx.x; e < PATCH_ELEMS; e += 256) {
        const int r = e / PATCH;          // 0..64 (compiler emits magic-mul)
        const int c = e - r * PATCH;      // 0..64
        const int R = R0 + r;
        const int C = C0 + c;
        if ((unsigned)R < 256u && (unsigned)C < 256u) {
            const float* p0 = coeffs + (r + 2) * CW + (c + 2);
            float v = 0.0f;
#pragma unroll
            for (int i = 0; i < 4; ++i) {
                const float* row = p0 + i * CW;
                const float s = row[0] * wy[0] + row[1] * wy[1] +
                                row[2] * wy[2] + row[3] * wy[3];
                v = fmaf(wx[i], s, v);
            }
            ob[R * 256 + C] = v;
        }
    }
}

extern "C" void kernel_launch(void* const* d_in, const int* in_sizes, int n_in,
                              void* d_out, int out_size, void* d_ws, size_t ws_size,
                              hipStream_t stream) {
    const float* coeffs = (const float*)d_in[0];  // (72,72)
    const float* x      = (const float*)d_in[1];  // (1024,)
    const float* y      = (const float*)d_in[2];  // (1024,)
    float* out = (float*)d_out;                   // (1024,1,256,256)

    // Zero the whole output (256 MiB) via the fast fill path, then overwrite
    // only the nonzero 65x65 patch of each image.
    hipMemsetAsync(out, 0, (size_t)out_size * sizeof(float), stream);

    const int batch = in_sizes[1];  // 1024
    spline2d_patch<<<batch, 256, 0, stream>>>(coeffs, x, y, out);
}